// Round 4
// baseline (26165.475 us; speedup 1.0000x reference)
//
#include <hip/hip_runtime.h>

#define NB 256
#define NT 1024

// problem dims
#define BB   64
#define TTS  2048
#define DKV  128
#define EEM  256
#define HH1  512
#define VVV  30
#define LLS  256
#define SOS_ID 1
#define SCALE_F 0.088388347648318447f  // 1/sqrt(128)

// ws float offsets
#define OFF_PM2   0        // 512  slice partial max  [b*8+s]
#define OFF_PS2   512      // 512  slice partial sum  [b*8+s]
#define OFF_PCTX2 1024     // 65536 slice partial ctx [d*512 + b*8 + s]
#define OFF_WSE   66560    // 2048 energies for b=0
#define OFF_ASG   68608    // 1024 int slots: nsl[64] @0, blk2b[256] @64, blk2s[256] @320
#define OFF_EMBT  69632    // 2*16384 embT double buffer [k*64+b]
#define OFF_H1    102400   // 2*32768 h1 double buffer [k*64+b]
#define OFF_H2T   167936   // 2*8192 h2 transposed [d*64+b]
#define OFF_BAR   184320   // 2048 uints
#define OFF_KBF   186368   // bf16 K: 16777216 ushorts (8388608 float slots)
#define OFF_VBF   8574976  // bf16 V
#define WS_NEED_BYTES 67854336ull
#define PRED_SZ   491520   // 64*256*30

struct Params {
  const float* key; const float* value;
  const int* enc_len; const int* y;
  const float* emb;
  const float* Wih1; const float* Whh1; const float* bih1; const float* bhh1;
  const float* Wih2; const float* Whh2; const float* bih2; const float* bhh2;
  const float* obias;
  float* out; float* ws;
};

struct SMEM {
  union {
    struct {
      float ctxT[8192];                      // [d*64 + b], 32 KB
      union { float wt[8192]; float red[8192]; } u;
    } a;
    struct { float wm[16]; float wS[16]; float wctx[2048]; } c;
  };
};

__device__ __forceinline__ float sigm(float x) { return 1.f / (1.f + __expf(-x)); }
__device__ __forceinline__ float tanh_f(float x) {
  float t = __expf(-2.f * fabsf(x));
  float r = (1.f - t) / (1.f + t);
  return x < 0.f ? -r : r;
}
__device__ __forceinline__ unsigned bfr(float f) {  // fp32 -> bf16 bits, RNE
  unsigned u = __float_as_uint(f);
  return (u + 0x7FFFu + ((u >> 16) & 1u)) >> 16;
}
__device__ __forceinline__ float b2f(unsigned short h) {
  return __uint_as_float(((unsigned)h) << 16);
}

// Hierarchical grid barrier; relaxed polls, one release fence in, one acquire out.
__device__ __forceinline__ void gbar(unsigned* base) {
  __syncthreads();
  if (threadIdx.x == 0) {
    __builtin_amdgcn_fence(__ATOMIC_RELEASE, "agent");
    unsigned* gen = base + 1056;
    unsigned g = __hip_atomic_load(gen, __ATOMIC_RELAXED, __HIP_MEMORY_SCOPE_AGENT);
    unsigned* gcnt = base + (blockIdx.x & 31) * 32;
    if (__hip_atomic_fetch_add(gcnt, 1u, __ATOMIC_RELAXED, __HIP_MEMORY_SCOPE_AGENT) == 7u) {
      unsigned* mcnt = base + 1024;
      if (__hip_atomic_fetch_add(mcnt, 1u, __ATOMIC_RELAXED, __HIP_MEMORY_SCOPE_AGENT) == 31u) {
        #pragma unroll
        for (int gg = 0; gg < 32; ++gg)
          __hip_atomic_store(base + gg * 32, 0u, __ATOMIC_RELAXED, __HIP_MEMORY_SCOPE_AGENT);
        __hip_atomic_store(mcnt, 0u, __ATOMIC_RELAXED, __HIP_MEMORY_SCOPE_AGENT);
        __hip_atomic_store(gen, g + 1u, __ATOMIC_RELEASE, __HIP_MEMORY_SCOPE_AGENT);
      }
    }
    int guard = 0;
    while (__hip_atomic_load(gen, __ATOMIC_RELAXED, __HIP_MEMORY_SCOPE_AGENT) == g) {
      __builtin_amdgcn_s_sleep(1);
      if (++guard > 50000000) break;
    }
    __builtin_amdgcn_fence(__ATOMIC_ACQUIRE, "agent");
  }
  __syncthreads();
}

__device__ __forceinline__ void mac8x4(float acc[8][4], const float* wt, int k, float4 x4) {
  float4 wa = *(const float4*)(wt + k*8);
  float4 wb = *(const float4*)(wt + k*8 + 4);
  float wr[8] = {wa.x, wa.y, wa.z, wa.w, wb.x, wb.y, wb.z, wb.w};
  float xr[4] = {x4.x, x4.y, x4.z, x4.w};
  #pragma unroll
  for (int r = 0; r < 8; ++r)
    #pragma unroll
    for (int c = 0; c < 4; ++c)
      acc[r][c] += wr[r] * xr[c];
}

__device__ __forceinline__ void gate_reduce_store(float acc[8][4], float* red, int tid) {
  #pragma unroll
  for (int r = 0; r < 8; ++r) {
    #pragma unroll
    for (int c = 0; c < 4; ++c) {
      float v = acc[r][c];
      v += __shfl_xor(v, 16);
      v += __shfl_xor(v, 32);
      acc[r][c] = v;
    }
  }
  int wv = tid >> 6, b0 = tid & 15;
  if ((tid & 63) < 16) {
    #pragma unroll
    for (int r = 0; r < 8; ++r)
      *(float4*)(red + wv*512 + r*64 + b0*4) =
        make_float4(acc[r][0], acc[r][1], acc[r][2], acc[r][3]);
  }
}

// wave-partials -> block partial -> (pm2, pS2, pctx2[d*512+b*8+s])
__device__ __forceinline__ void attn_combine(SMEM* sm, float m, float S, float4 ca,
                                             int lane, int w, int sub, int grp, int tid,
                                             float* pm2, float* pS2, float* pctx2,
                                             int bb, int s) {
  float mo = __shfl_xor(m, 32);
  float M2 = fmaxf(m, mo);
  float as_ = __expf(m - M2), ao = __expf(mo - M2);
  float S2 = S*as_ + __shfl_xor(S, 32)*ao;
  float cx = ca.x*as_ + __shfl_xor(ca.x, 32)*ao;
  float cy = ca.y*as_ + __shfl_xor(ca.y, 32)*ao;
  float cz = ca.z*as_ + __shfl_xor(ca.z, 32)*ao;
  float cw = ca.w*as_ + __shfl_xor(ca.w, 32)*ao;
  if (lane == 0) { sm->c.wm[w] = M2; sm->c.wS[w] = S2; }
  if (grp == 0)
    *(float4*)(sm->c.wctx + w*DKV + sub*4) = make_float4(cx, cy, cz, cw);
  __syncthreads();
  if (tid < DKV) {
    int d = tid;
    float M = -1e30f;
    #pragma unroll
    for (int ww = 0; ww < 16; ++ww) M = fmaxf(M, sm->c.wm[ww]);
    float Z = 0.f, acc2 = 0.f;
    #pragma unroll
    for (int ww = 0; ww < 16; ++ww) {
      float aw = __expf(sm->c.wm[ww] - M);
      Z += aw * sm->c.wS[ww];
      acc2 += aw * sm->c.wctx[ww*DKV + d];
    }
    pctx2[d*512 + bb*8 + s] = acc2;
    if (d == 0) { pm2[bb*8 + s] = M; pS2[bb*8 + s] = Z; }
  }
  __syncthreads();
}

// setup-only: mean over full T (fixed mapping b=bj>>2, s=bj&3), fp32 V
__device__ void phase_attn_mean(const Params& p, float* pm2, float* pS2, float* pctx2,
                                SMEM* sm, int bj, int tid) {
  const int lane = tid & 63, w = tid >> 6;
  const int b = bj >> 2, s = bj & 3;
  const int sub = lane & 31, grp = lane >> 5;
  float S = 0.f;
  float4 ca = make_float4(0.f, 0.f, 0.f, 0.f);
  const int t0 = (4*w + s) * 32;
  const float* vb = p.value + (size_t)b * TTS * DKV;
  for (int tt = 0; tt < 32; tt += 2) {
    int t = t0 + tt + grp;
    float4 v4 = *(const float4*)(vb + (size_t)t*DKV + sub*4);
    S += 1.f;
    ca.x += v4.x; ca.y += v4.y; ca.z += v4.z; ca.w += v4.w;
  }
  attn_combine(sm, 0.f, S, ca, lane, w, sub, grp, tid, pm2, pS2, pctx2, b, s);
}

// balanced online-softmax attention; 2-deep chunk pipeline
template<bool BF16>
__device__ void phase_attn_bal(const Params& p, const float* h2t,
                               const unsigned short* kbf, const unsigned short* vbf,
                               float* pm2, float* pS2, float* pctx2, float* wsE,
                               const int* asg, SMEM* sm, int bj, int tid) {
  const int lane = tid & 63, w = tid >> 6;
  const int sub = lane & 31, grp = lane >> 5;
  const int bb = asg[64 + bj];
  if (bb < 0) return;                 // block-uniform
  const int s = asg[320 + bj];
  const int n = asg[bb];
  const int len = p.enc_len[bb];
  const int R = (len + 31) >> 5;
  const int s0 = (s*R)/n, s1 = ((s+1)*R)/n;
  const int ns = s1 - s0;
  const float q0 = h2t[(sub*4+0)*64 + bb];
  const float q1 = h2t[(sub*4+1)*64 + bb];
  const float q2 = h2t[(sub*4+2)*64 + bb];
  const float q3 = h2t[(sub*4+3)*64 + bb];
  float m = -1e30f, S = 0.f;
  float4 ca = make_float4(0.f, 0.f, 0.f, 0.f);
  const int np = ns;                   // row-pairs per wave (wave w gets 2*ns rows)
  const int rbase = s0*32 + w*2*ns;

  if (np > 0) {
    const unsigned short* kb = kbf + (size_t)bb * TTS * DKV;
    const unsigned short* vb = vbf + (size_t)bb * TTS * DKV;
    const float* kbf32 = p.key + (size_t)bb * TTS * DKV;
    const float* vbf32 = p.value + (size_t)bb * TTS * DKV;

    ushort4 kA[4], vA[4]; float4 kA32[4], vA32[4]; int tA[4]; bool aA[4];
    ushort4 kB[4], vB[4]; float4 kB32[4], vB32[4]; int tB[4]; bool aB[4];

    auto ld = [&](int c0, ushort4* K, ushort4* V, float4* K32, float4* V32,
                  int* T_, bool* VA) {
      #pragma unroll
      for (int j = 0; j < 4; ++j) {
        int jj = c0 + j;
        int jr = jj < np ? jj : (np - 1);
        int t = rbase + 2*jr + grp;
        int tc = t < TTS ? t : TTS - 1;
        VA[j] = (jj < np) && (t < len);
        T_[j] = t;
        size_t off = (size_t)tc*DKV + sub*4;
        if constexpr (BF16) {
          K[j] = *(const ushort4*)(kb + off);
          V[j] = *(const ushort4*)(vb + off);
        } else {
          K32[j] = *(const float4*)(kbf32 + off);
          V32[j] = *(const float4*)(vbf32 + off);
        }
      }
    };

    ld(0, kA, vA, kA32, vA32, tA, aA);
    for (int c0 = 0; c0 < np; c0 += 4) {
      bool haveB = (c0 + 4) < np;
      if (haveB) ld(c0 + 4, kB, vB, kB32, vB32, tB, aB);
      float e[4], vx[4][4];
      #pragma unroll
      for (int j = 0; j < 4; ++j) {
        float kx, ky, kz, kw;
        if constexpr (BF16) {
          kx = b2f(kA[j].x); ky = b2f(kA[j].y); kz = b2f(kA[j].z); kw = b2f(kA[j].w);
          vx[j][0] = b2f(vA[j].x); vx[j][1] = b2f(vA[j].y);
          vx[j][2] = b2f(vA[j].z); vx[j][3] = b2f(vA[j].w);
        } else {
          kx = kA32[j].x; ky = kA32[j].y; kz = kA32[j].z; kw = kA32[j].w;
          vx[j][0] = vA32[j].x; vx[j][1] = vA32[j].y;
          vx[j][2] = vA32[j].z; vx[j][3] = vA32[j].w;
        }
        float ep = q0*kx + q1*ky + q2*kz + q3*kw;
        ep += __shfl_xor(ep, 1); ep += __shfl_xor(ep, 2); ep += __shfl_xor(ep, 4);
        ep += __shfl_xor(ep, 8); ep += __shfl_xor(ep, 16);
        e[j] = aA[j] ? ep * SCALE_F : -1e30f;
        if (bb == 0 && aA[j] && sub == 0) wsE[tA[j]] = e[j];
      }
      float mc = fmaxf(fmaxf(e[0], e[1]), fmaxf(e[2], e[3]));
      float mn = fmaxf(m, mc);
      float al = __expf(m - mn);
      float pr[4];
      #pragma unroll
      for (int j = 0; j < 4; ++j) pr[j] = aA[j] ? __expf(e[j] - mn) : 0.f;
      S = S*al + pr[0] + pr[1] + pr[2] + pr[3];
      ca.x = ca.x*al + pr[0]*vx[0][0] + pr[1]*vx[1][0] + pr[2]*vx[2][0] + pr[3]*vx[3][0];
      ca.y = ca.y*al + pr[0]*vx[0][1] + pr[1]*vx[1][1] + pr[2]*vx[2][1] + pr[3]*vx[3][1];
      ca.z = ca.z*al + pr[0]*vx[0][2] + pr[1]*vx[1][2] + pr[2]*vx[2][2] + pr[3]*vx[3][2];
      ca.w = ca.w*al + pr[0]*vx[0][3] + pr[1]*vx[1][3] + pr[2]*vx[2][3] + pr[3]*vx[3][3];
      m = mn;
      if (haveB) {
        #pragma unroll
        for (int j = 0; j < 4; ++j) {
          kA[j] = kB[j]; vA[j] = vB[j];
          kA32[j] = kB32[j]; vA32[j] = vB32[j];
          tA[j] = tB[j]; aA[j] = aB[j];
        }
      }
    }
  }
  attn_combine(sm, m, S, ca, lane, w, sub, grp, tid, pm2, pS2, pctx2, bb, s);
}

template<bool BF16>
__global__ void __launch_bounds__(NT, 4) decoder_kernel(Params p) {
  const int tid = threadIdx.x;
  const int bj = blockIdx.x;
  float* ws = p.ws;
  unsigned* bar = (unsigned*)(ws + OFF_BAR);
  float* pm2 = ws + OFF_PM2;
  float* pS2 = ws + OFF_PS2;
  float* pctx2 = ws + OFF_PCTX2;
  float* wsE = ws + OFF_WSE;
  int* asg = (int*)(ws + OFF_ASG);
  float* embT0 = ws + OFF_EMBT;
  float* embT1 = ws + OFF_EMBT + EEM*BB;
  float* h1b0 = ws + OFF_H1;
  float* h1b1 = ws + OFF_H1 + HH1*BB;
  float* h2t0 = ws + OFF_H2T;
  float* h2t1 = ws + OFF_H2T + DKV*BB;
  unsigned short* kbf = (unsigned short*)(ws + OFF_KBF);
  unsigned short* vbf = (unsigned short*)(ws + OFF_VBF);

  __shared__ SMEM sm;

  // persistent registers: weights, biases, cell states
  float wr1[8] = {0,0,0,0,0,0,0,0};
  if (tid < 896) {
    #pragma unroll
    for (int r = 0; r < 8; ++r) {
      int grow = (r >> 1)*HH1 + 2*bj + (r & 1);
      wr1[r] = (tid < 384) ? p.Wih1[(size_t)grow*384 + tid]
                           : p.Whh1[(size_t)grow*HH1 + (tid - 384)];
    }
  }
  float wr2[8] = {0,0,0,0,0,0,0,0};
  if (bj < 64 && tid < 640) {
    #pragma unroll
    for (int r = 0; r < 8; ++r) {
      int grow = (r >> 1)*DKV + 2*bj + (r & 1);
      wr2[r] = (tid < 512) ? p.Wih2[(size_t)grow*HH1 + tid]
                           : p.Whh2[(size_t)grow*DKV + (tid - 512)];
    }
  }
  float bsum1 = 0.f, bsum2 = 0.f;
  if (tid < 512) {
    int r = tid >> 6;
    int g1 = (r >> 1)*HH1 + 2*bj + (r & 1);
    bsum1 = p.bih1[g1] + p.bhh1[g1];
    if (bj < 64) {
      int g2 = (r >> 1)*DKV + 2*bj + (r & 1);
      bsum2 = p.bih2[g2] + p.bhh2[g2];
    }
  }
  float c1r = 0.f, c2r = 0.f;   // cell states (tid<128 owns [hh][b])

  // ---------------- setup ----------------
  {
    int gid = bj*NT + tid;
    for (int idx = gid; idx < (OFF_BAR - OFF_H1); idx += NB*NT) ws[OFF_H1 + idx] = 0.f;
    for (int idx = gid; idx < EEM*BB; idx += NB*NT) {
      int k = idx >> 6, b = idx & 63;
      embT0[k*64 + b] = p.emb[SOS_ID*EEM + k];
    }
    if (bj == 0 && tid == 0) {
      // length-proportional slice assignment (lens are launch-constant)
      int R[64], n[64], cp[64]; long G = 0;
      for (int b = 0; b < 64; ++b) { int L = p.enc_len[b]; R[b] = (L + 31) >> 5; G += R[b]; }
      int used = 0;
      for (int b = 0; b < 64; ++b) {
        int cap = R[b] < 8 ? R[b] : 8; cp[b] = cap;
        int v = (int)(((long)R[b] * 256) / G);
        if (v < 1) v = 1; if (v > cap) v = cap;
        n[b] = v; used += v;
      }
      while (used < 256) {
        int best = -1; float bv = -1.f;
        for (int b = 0; b < 64; ++b) if (n[b] < cp[b]) {
          float v = (float)R[b] / (float)n[b];
          if (v > bv) { bv = v; best = b; }
        }
        if (best < 0) break;
        n[best]++; used++;
      }
      while (used > 256) {
        int best = -1; float bv = 1e30f;
        for (int b = 0; b < 64; ++b) if (n[b] > 1) {
          float v = (float)R[b] / (float)n[b];
          if (v < bv) { bv = v; best = b; }
        }
        n[best]--; used--;
      }
      for (int j = 0; j < 256; ++j) { asg[64 + j] = -1; asg[320 + j] = 0; }
      int j = 0;
      for (int b = 0; b < 64; ++b) {
        asg[b] = n[b];
        for (int s = 0; s < n[b] && j < 256; ++s) { asg[64 + j] = b; asg[320 + j] = s; ++j; }
      }
    }
    if constexpr (BF16) {
      const int NG = (BB*TTS*DKV) / 8;
      for (int g = gid; g < NG; g += NB*NT) {
        const float4* src = (const float4*)p.key + (size_t)g*2;
        float4 a = src[0], bq = src[1];
        uint4 o;
        o.x = bfr(a.x)  | (bfr(a.y)  << 16);
        o.y = bfr(a.z)  | (bfr(a.w)  << 16);
        o.z = bfr(bq.x) | (bfr(bq.y) << 16);
        o.w = bfr(bq.z) | (bfr(bq.w) << 16);
        ((uint4*)kbf)[g] = o;
      }
      for (int g = gid; g < NG; g += NB*NT) {
        const float4* src = (const float4*)p.value + (size_t)g*2;
        float4 a = src[0], bq = src[1];
        uint4 o;
        o.x = bfr(a.x)  | (bfr(a.y)  << 16);
        o.y = bfr(a.z)  | (bfr(a.w)  << 16);
        o.z = bfr(bq.x) | (bfr(bq.y) << 16);
        o.w = bfr(bq.z) | (bfr(bq.w) << 16);
        ((uint4*)vbf)[g] = o;
      }
    }
    phase_attn_mean(p, pm2, pS2, pctx2, &sm, bj, tid);
  }
  gbar(bar);

  for (int i = 0; i <= LLS; ++i) {
    const int cur = i & 1;
    float* h1c = cur ? h1b1 : h1b0;
    const float* h1p = cur ? h1b0 : h1b1;
    float* h2tc = cur ? h2t1 : h2t0;
    const float* h2tp = cur ? h2t0 : h2t1;
    const float* et = cur ? embT1 : embT0;
    float* etn = cur ? embT0 : embT1;

    // ================= phase A =================
    // A0: combine variable slice partials -> ctxT [d][b]
    {
      int b = tid & 63, dg = tid >> 6;
      int nc = (i == 0) ? 4 : asg[b];
      float M = -1e30f;
      for (int s = 0; s < nc; ++s) M = fmaxf(M, pm2[b*8 + s]);
      float aa[8]; float Z = 0.f;
      for (int s = 0; s < nc; ++s) {
        aa[s] = __expf(pm2[b*8 + s] - M);
        Z += aa[s] * pS2[b*8 + s];
      }
      float iZ = 1.f / Z;
      #pragma unroll
      for (int jj = 0; jj < 8; ++jj) {
        int d = dg + jj*16;
        float acc = 0.f;
        for (int s = 0; s < nc; ++s) acc += aa[s] * pctx2[d*512 + b*8 + s];
        sm.a.ctxT[d*64 + b] = acc * iZ;
      }
    }
    if (i < LLS && tid < 896) {   // stage W1 rows from registers
      *(float4*)(sm.a.u.wt + tid*8)     = make_float4(wr1[0], wr1[1], wr1[2], wr1[3]);
      *(float4*)(sm.a.u.wt + tid*8 + 4) = make_float4(wr1[4], wr1[5], wr1[6], wr1[7]);
    }
    __syncthreads();

    if (i < LLS) {
      // A1: LSTM1 gates for h in {2bj, 2bj+1}
      {
        const int b0 = tid & 15, ks = tid >> 4;
        float acc[8][4];
        #pragma unroll
        for (int r = 0; r < 8; ++r) { acc[r][0]=0.f; acc[r][1]=0.f; acc[r][2]=0.f; acc[r][3]=0.f; }
        #pragma unroll
        for (int j = 0; j < 4; ++j) {
          int k = ks*4 + j;
          float4 x4 = *(const float4*)(et + k*64 + b0*4);
          mac8x4(acc, sm.a.u.wt, k, x4);
        }
        #pragma unroll
        for (int j = 0; j < 2; ++j) {
          int d = ks*2 + j;
          float4 x4 = *(const float4*)(sm.a.ctxT + d*64 + b0*4);
          mac8x4(acc, sm.a.u.wt, 256 + d, x4);
        }
        #pragma unroll
        for (int j = 0; j < 8; ++j) {
          int kk = ks*8 + j;
          float4 x4 = *(const float4*)(h1p + kk*64 + b0*4);
          mac8x4(acc, sm.a.u.wt, 384 + kk, x4);
        }
        __syncthreads();
        gate_reduce_store(acc, sm.a.u.red, tid);
      }
      __syncthreads();
      if (tid < 512) {
        int r = tid >> 6, b = tid & 63;
        float s = 0.f;
        #pragma unroll
        for (int w2 = 0; w2 < 16; ++w2) s += sm.a.u.red[w2*512 + r*64 + b];
        s += bsum1;
        sm.a.u.red[r*64 + b] = s;
      }
      __syncthreads();
      if (tid < 128) {
        int hh = tid >> 6, b = tid & 63;
        int h = 2*bj + hh;
        float gi = sm.a.u.red[(hh+0)*64 + b];
        float gf = sm.a.u.red[(hh+2)*64 + b];
        float gg = sm.a.u.red[(hh+4)*64 + b];
        float go = sm.a.u.red[(hh+6)*64 + b];
        float cn = sigm(gf)*c1r + sigm(gi)*tanh_f(gg);
        float hn = sigm(go)*tanh_f(cn);
        c1r = cn;
        h1c[h*64 + b] = hn;
      }
    }

    if (i >= 1) {
      // A2: logits step i-1 (query=h2(i-1) in h2tp, ctx(i-1) in ctxT)
      if (tid >= 960) {
        int ln = tid - 960;
        int oi = bj*8 + (ln >> 3);
        int sub = ln & 7;
        if (oi < BB*VVV) {
          int b = oi / VVV, v = oi - b*VVV;
          float a = 0.f;
          if (sub < 4) {
            #pragma unroll 8
            for (int e0 = 0; e0 < 32; ++e0) {
              int e = sub*32 + e0;
              a += h2tp[e*64 + b] * p.emb[v*EEM + e];
            }
          } else {
            #pragma unroll 8
            for (int e0 = 0; e0 < 32; ++e0) {
              int d = (sub - 4)*32 + e0;
              a += sm.a.ctxT[d*64 + b] * p.emb[v*EEM + 128 + d];
            }
          }
          a += __shfl_xor(a, 1); a += __shfl_xor(a, 2); a += __shfl_xor(a, 4);
          if (sub == 0) p.out[((size_t)b*LLS + (i-1))*VVV + v] = a + p.obias[v];
        }
      }
      // A3: attention plot row i-1 (variable slice count for b=0)
      if (tid >= 896 && tid < 904) {
        int t = bj*8 + (tid - 896);
        int len0 = p.enc_len[0];
        float v = 0.f;
        if (t < len0) {
          int n0 = asg[0];
          float M = -1e30f;
          for (int s = 0; s < n0; ++s) M = fmaxf(M, pm2[s]);
          float Z = 0.f;
          for (int s = 0; s < n0; ++s) Z += __expf(pm2[s] - M) * pS2[s];
          v = __expf(wsE[t] - M) / Z;
        }
        p.out[PRED_SZ + (size_t)(i-1)*TTS + t] = v;
      }
    }

    if (i == LLS) break;
    gbar(bar);

    // ================= phase B =================
    if (bj < 64) {
      if (tid < 640) {
        *(float4*)(sm.a.u.wt + tid*8)     = make_float4(wr2[0], wr2[1], wr2[2], wr2[3]);
        *(float4*)(sm.a.u.wt + tid*8 + 4) = make_float4(wr2[4], wr2[5], wr2[6], wr2[7]);
      }
      __syncthreads();
      {
        const int b0 = tid & 15, ks = tid >> 4;
        float acc[8][4];
        #pragma unroll
        for (int r = 0; r < 8; ++r) { acc[r][0]=0.f; acc[r][1]=0.f; acc[r][2]=0.f; acc[r][3]=0.f; }
        #pragma unroll
        for (int j = 0; j < 8; ++j) {
          int k = ks*8 + j;
          float4 x4 = *(const float4*)(h1c + k*64 + b0*4);
          mac8x4(acc, sm.a.u.wt, k, x4);
        }
        #pragma unroll
        for (int j = 0; j < 2; ++j) {
          int d = ks*2 + j;
          float4 x4 = *(const float4*)(h2tp + d*64 + b0*4);
          mac8x4(acc, sm.a.u.wt, 512 + d, x4);
        }
        __syncthreads();
        gate_reduce_store(acc, sm.a.u.red, tid);
      }
      __syncthreads();
      if (tid < 512) {
        int r = tid >> 6, b = tid & 63;
        float s = 0.f;
        #pragma unroll
        for (int w2 = 0; w2 < 16; ++w2) s += sm.a.u.red[w2*512 + r*64 + b];
        s += bsum2;
        sm.a.u.red[r*64 + b] = s;
      }
      __syncthreads();
      if (tid < 128) {
        int hh = tid >> 6, b = tid & 63;
        int d2 = 2*bj + hh;
        float gi = sm.a.u.red[(hh+0)*64 + b];
        float gf = sm.a.u.red[(hh+2)*64 + b];
        float gg = sm.a.u.red[(hh+4)*64 + b];
        float go = sm.a.u.red[(hh+6)*64 + b];
        float cn = sigm(gf)*c2r + sigm(gi)*tanh_f(gg);
        float hn = sigm(go)*tanh_f(cn);
        c2r = cn;
        h2tc[d2*64 + b] = hn;
      }
    } else if (bj < 128) {
      int sn = i + 1;
      if (sn < LLS && tid < 256) {
        int idx = (bj - 64)*256 + tid;
        int k = idx >> 6, b = idx & 63;
        int id = p.y[b*LLS + sn - 1];
        etn[k*64 + b] = p.emb[(size_t)id*EEM + k];
      }
    }
    gbar(bar);

    // ================= phase C =================
    phase_attn_bal<BF16>(p, h2tc, kbf, vbf, pm2, pS2, pctx2, wsE, asg, &sm, bj, tid);
    gbar(bar);
  }
}

__global__ void init_bar_kernel(unsigned* bar) {
  int i = blockIdx.x * blockDim.x + threadIdx.x;
  if (i < 2048) bar[i] = 0u;
}

extern "C" void kernel_launch(void* const* d_in, const int* in_sizes, int n_in,
                              void* d_out, int out_size, void* d_ws, size_t ws_size,
                              hipStream_t stream) {
  Params prm;
  prm.key     = (const float*)d_in[0];
  prm.value   = (const float*)d_in[1];
  prm.enc_len = (const int*)d_in[2];
  prm.y       = (const int*)d_in[3];
  prm.emb     = (const float*)d_in[4];
  prm.Wih1    = (const float*)d_in[5];
  prm.Whh1    = (const float*)d_in[6];
  prm.bih1    = (const float*)d_in[7];
  prm.bhh1    = (const float*)d_in[8];
  prm.Wih2    = (const float*)d_in[9];
  prm.Whh2    = (const float*)d_in[10];
  prm.bih2    = (const float*)d_in[11];
  prm.bhh2    = (const float*)d_in[12];
  prm.obias   = (const float*)d_in[13];
  prm.out = (float*)d_out;
  prm.ws  = (float*)d_ws;

  unsigned* bar = (unsigned*)((float*)d_ws + OFF_BAR);
  init_bar_kernel<<<8, 256, 0, stream>>>(bar);

  void* args[] = { &prm };
  if (ws_size >= WS_NEED_BYTES) {
    hipError_t e = hipLaunchCooperativeKernel((const void*)decoder_kernel<true>,
                                              dim3(NB), dim3(NT), args, 0, stream);
    if (e != hipSuccess) decoder_kernel<true><<<dim3(NB), dim3(NT), 0, stream>>>(prm);
  } else {
    hipError_t e = hipLaunchCooperativeKernel((const void*)decoder_kernel<false>,
                                              dim3(NB), dim3(NT), args, 0, stream);
    if (e != hipSuccess) decoder_kernel<false><<<dim3(NB), dim3(NT), 0, stream>>>(prm);
  }
}